// Round 6
// baseline (444.281 us; speedup 1.0000x reference)
//
#include <hip/hip_runtime.h>
#include <hip/hip_bf16.h>
#include <hip/hip_cooperative_groups.h>

namespace cg = cooperative_groups;

#define B_ 256
#define L_ 100
#define F_ 8
#define P_ 4
#define E_ 64
#define H_ 4
#define D_ 64
#define C_ 32
#define V_ 10000
#define TOWER_IN_ 1312
#define LN_EPS 0.001f
#define LCH_ 2    // l's per attention block
#define NCH_ 50   // number of l-chunks

typedef __attribute__((ext_vector_type(8))) short bf8v;   // 8 bf16 (4 VGPRs)
typedef __attribute__((ext_vector_type(4))) float f4v;    // 4 f32 acc

__device__ __forceinline__ unsigned short f2bf(float x) {
    __hip_bfloat16 h = __float2bfloat16(x);
    return __builtin_bit_cast(unsigned short, h);
}

// ---------------------------------------------------------------------------
// Kernel S: fused setup.  grid = 2368 blocks, 256 thr.
//   bx < 1952          : transpose tower weights to bf16 [n][k]
//   1952 <= bx < 2352  : precompute MT/WT (MFMA)
//   bx >= 2352         : zero ubs_acc
// ---------------------------------------------------------------------------
__global__ __launch_bounds__(256) void setup_kernel(
    const float* __restrict__ q_w, const float* __restrict__ k_w,
    const float* __restrict__ v_w, const float* __restrict__ lin_w,
    const float* __restrict__ w1, const float* __restrict__ w2,
    const float* __restrict__ w3,
    unsigned short* __restrict__ wsMT, unsigned short* __restrict__ wsWT,
    unsigned short* __restrict__ Wt1, unsigned short* __restrict__ Wt2,
    unsigned short* __restrict__ Wt3, float* __restrict__ ubs_acc)
{
    __shared__ float tile[32][33];
    __shared__ __align__(16) unsigned short sX[64][72];
    __shared__ __align__(16) unsigned short sY[64][72];
    const int bx = blockIdx.x, t = threadIdx.x;

    if (bx < 1952) {
        // ---- weight transpose ----
        const float* src; unsigned short* dst; int K, N, tk, tn;
        if (bx < 1312)      { src = w1; dst = Wt1; K = 1312; N = 1024; tk = bx / 32;  tn = bx % 32; }
        else if (bx < 1824) { int i = bx - 1312; src = w2; dst = Wt2; K = 1024; N = 512; tk = i / 16; tn = i % 16; }
        else                { int i = bx - 1824; src = w3; dst = Wt3; K = 512;  N = 256; tk = i / 8;  tn = i % 8; }
        const int k0 = tk * 32, n0 = tn * 32;
        const int rr = t >> 5, cc = t & 31;
        #pragma unroll
        for (int i = 0; i < 4; ++i) {
            int r = rr * 4 + i;
            tile[r][cc] = src[(size_t)(k0 + r) * N + n0 + cc];
        }
        __syncthreads();
        #pragma unroll
        for (int i = 0; i < 4; ++i) {
            int r = rr * 4 + i;
            dst[(size_t)(n0 + r) * K + k0 + cc] = f2bf(tile[cc][r]);
        }
    } else if (bx < 2352) {
        // ---- precompute MT[o][e] = sum_d Q[e][d]K[o][d],
        //                 WT[o][e] = sum_d L[d][o]V[e][d]  via MFMA ----
        const int lh = bx - 1952;
        const int l = lh >> 2, h = lh & 3;
        const size_t obase = (size_t)lh * 4096;
        const int wv = t >> 6, lane = t & 63, quad = lane >> 4, cl = lane & 15;
        const int r = t >> 2, seg = t & 3, e0s = seg * 16;

        // phase 1: sX = K rows, sY = Q rows
        #pragma unroll
        for (int j = 0; j < 8; ++j) {
            const float* kp = k_w + (size_t)(l * 64 + r) * 256 + h * 64 + e0s + 2 * j;
            const float* qp = q_w + (size_t)(l * 64 + r) * 256 + h * 64 + e0s + 2 * j;
            *(unsigned*)&sX[r][e0s + 2 * j] = (unsigned)f2bf(kp[0]) | ((unsigned)f2bf(kp[1]) << 16);
            *(unsigned*)&sY[r][e0s + 2 * j] = (unsigned)f2bf(qp[0]) | ((unsigned)f2bf(qp[1]) << 16);
        }
        __syncthreads();
        {
            const int o0 = wv * 16;
            #pragma unroll
            for (int nt = 0; nt < 4; ++nt) {
                f4v acc = {0.f, 0.f, 0.f, 0.f};
                #pragma unroll
                for (int k2 = 0; k2 < 2; ++k2) {
                    bf8v a = *(const bf8v*)&sX[o0 + cl][k2 * 32 + quad * 8];
                    bf8v b = *(const bf8v*)&sY[nt * 16 + cl][k2 * 32 + quad * 8];
                    acc = __builtin_amdgcn_mfma_f32_16x16x32_bf16(a, b, acc, 0, 0, 0);
                }
                #pragma unroll
                for (int j = 0; j < 4; ++j)
                    wsMT[obase + (size_t)(o0 + quad * 4 + j) * 64 + nt * 16 + cl] = f2bf(acc[j]);
            }
        }
        __syncthreads();
        // phase 2: sX = L^T rows [o][d], sY = V rows [e][d]
        {
            const int o = t & 63, db = t >> 6;
            #pragma unroll
            for (int j = 0; j < 16; ++j) {
                int d = db * 16 + j;
                sX[o][d] = f2bf(lin_w[(size_t)l * 16384 + (h * 64 + d) * 64 + o]);
            }
        }
        #pragma unroll
        for (int j = 0; j < 8; ++j) {
            const float* vp = v_w + (size_t)(l * 64 + r) * 256 + h * 64 + e0s + 2 * j;
            *(unsigned*)&sY[r][e0s + 2 * j] = (unsigned)f2bf(vp[0]) | ((unsigned)f2bf(vp[1]) << 16);
        }
        __syncthreads();
        {
            const int o0 = wv * 16;
            #pragma unroll
            for (int nt = 0; nt < 4; ++nt) {
                f4v acc = {0.f, 0.f, 0.f, 0.f};
                #pragma unroll
                for (int k2 = 0; k2 < 2; ++k2) {
                    bf8v a = *(const bf8v*)&sX[o0 + cl][k2 * 32 + quad * 8];
                    bf8v b = *(const bf8v*)&sY[nt * 16 + cl][k2 * 32 + quad * 8];
                    acc = __builtin_amdgcn_mfma_f32_16x16x32_bf16(a, b, acc, 0, 0, 0);
                }
                #pragma unroll
                for (int j = 0; j < 4; ++j)
                    wsWT[obase + (size_t)(o0 + quad * 4 + j) * 64 + nt * 16 + cl] = f2bf(acc[j]);
            }
        }
    } else {
        // ---- zero ubs_acc ----
        const int idx = (bx - 2352) * 256 + t;
        for (int i = idx; i < B_ * F_ * E_; i += 16 * 256) ubs_acc[i] = 0.f;
    }
}

// ---------------------------------------------------------------------------
// Kernel A: fused attention, MFMA for everything but softmax.
// grid = NCH_*32 blocks (block = 8 b's x LCH_ l's), 256 threads = 4 waves.
// ---------------------------------------------------------------------------
__global__ __launch_bounds__(256, 3) void attn_kernel(
    const int* __restrict__ ubs_feature, const float* __restrict__ item_tables,
    const unsigned short* __restrict__ wsMT, const unsigned short* __restrict__ wsWT,
    const float* __restrict__ lin_b, const float* __restrict__ ln_g,
    const float* __restrict__ ln_b, float* __restrict__ ubs_acc)
{
    __shared__ __align__(16) unsigned short sUE[64][72];       // rows=b_loc*8+f
    __shared__ __align__(16) unsigned short sT[64][136];       // cols=hl*64+e'
    __shared__ __align__(16) unsigned short sZt[4][64][40];    // [pair][e][k] (pad 40)
    __shared__ __align__(16) unsigned short sAblk[4][16][40];  // [pair][r][k] (pad 40)
    __shared__ float sLng[64], sLnb[64], sLinb[64];

    const int t = threadIdx.x;
    const int c = blockIdx.x >> 5;            // l-chunk 0..NCH_-1
    const int b0 = (blockIdx.x & 31) * 8;
    const int wv = t >> 6, lane = t & 63, quad = lane >> 4, cl = lane & 15;
    const int grow = t >> 2, gseg = t & 3, ge0 = gseg * 16;   // gather mapping
    const int gbl = grow >> 3, gfq = grow & 7;
    const int gbg = b0 + gbl;

    if (t < 64) { sLng[t] = ln_g[t]; sLnb[t] = ln_b[t]; }

    float lnacc[16];
    #pragma unroll
    for (int i = 0; i < 16; ++i) lnacc[i] = 0.f;

    // prefetch gather for first l
    float2 pf[8];
    {
        const int l = c * LCH_;
        const int vidx = ubs_feature[(gbg * L_ + l) * F_ + gfq];
        const float* srcp = item_tables + ((size_t)gfq * V_ + vidx) * 64 + ge0;
        #pragma unroll
        for (int j = 0; j < 8; ++j) pf[j] = *(const float2*)(srcp + 2 * j);
    }

    for (int li = 0; li < LCH_; ++li) {
        const int l = c * LCH_ + li;
        if (t >= 64 && t < 128) sLinb[t - 64] = lin_b[l * 64 + (t - 64)];

        // ---- commit prefetched UE rows (f32 -> bf16) ----
        #pragma unroll
        for (int j = 0; j < 8; ++j) {
            unsigned u = (unsigned)f2bf(pf[j].x) | ((unsigned)f2bf(pf[j].y) << 16);
            *(unsigned*)&sUE[grow][ge0 + 2 * j] = u;
        }
        __syncthreads();

        // ---- prefetch next l's gather (latency hidden behind compute) ----
        if (li + 1 < LCH_) {
            const int ln = l + 1;
            const int vidx = ubs_feature[(gbg * L_ + ln) * F_ + gfq];
            const float* srcp = item_tables + ((size_t)gfq * V_ + vidx) * 64 + ge0;
            #pragma unroll
            for (int j = 0; j < 8; ++j) pf[j] = *(const float2*)(srcp + 2 * j);
        }

        f4v accO[4];
        #pragma unroll
        for (int nt = 0; nt < 4; ++nt) accO[nt] = {0.f, 0.f, 0.f, 0.f};

        for (int half = 0; half < 2; ++half) {
            // ---- phase A: waves 0,1 -> T (h=hl); waves 2,3 -> Zt (h=hl) ----
            {
                const int role = wv >> 1;     // 0=T, 1=Z
                const int hl = wv & 1;
                const unsigned short* Bsrc =
                    (role == 0 ? wsMT : wsWT) + (size_t)(l * 4 + half * 2 + hl) * 4096;
                bf8v bfrag[4][2];
                #pragma unroll
                for (int nt = 0; nt < 4; ++nt)
                    #pragma unroll
                    for (int k2 = 0; k2 < 2; ++k2)
                        bfrag[nt][k2] = *(const bf8v*)(Bsrc + (nt * 16 + cl) * 64 + k2 * 32 + quad * 8);
                #pragma unroll
                for (int m = 0; m < 4; ++m) {
                    bf8v a0 = *(const bf8v*)&sUE[m * 16 + cl][quad * 8];
                    bf8v a1 = *(const bf8v*)&sUE[m * 16 + cl][32 + quad * 8];
                    #pragma unroll
                    for (int nt = 0; nt < 4; ++nt) {
                        f4v acc = {0.f, 0.f, 0.f, 0.f};
                        acc = __builtin_amdgcn_mfma_f32_16x16x32_bf16(a0, bfrag[nt][0], acc, 0, 0, 0);
                        acc = __builtin_amdgcn_mfma_f32_16x16x32_bf16(a1, bfrag[nt][1], acc, 0, 0, 0);
                        if (role == 0) {
                            #pragma unroll
                            for (int j = 0; j < 4; ++j)
                                sT[m * 16 + quad * 4 + j][hl * 64 + nt * 16 + cl] = f2bf(acc[j]);
                        } else {
                            ushort4 zp;
                            zp.x = f2bf(acc[0]); zp.y = f2bf(acc[1]);
                            zp.z = f2bf(acc[2]); zp.w = f2bf(acc[3]);
                            const int k0 = (quad >> 1) * 16 + hl * 8 + (quad & 1) * 4;
                            *(ushort4*)&sZt[m][nt * 16 + cl][k0] = zp;
                        }
                    }
                }
            }
            __syncthreads();

            // ---- scores + softmax + Ablk (wave = pair) ----
            {
                const int p = wv;
                const bool valid = (cl >> 3) == (quad >> 1);
                #pragma unroll
                for (int hl = 0; hl < 2; ++hl) {
                    bf8v a0 = *(const bf8v*)&sT[p * 16 + cl][hl * 64 + quad * 8];
                    bf8v a1 = *(const bf8v*)&sT[p * 16 + cl][hl * 64 + 32 + quad * 8];
                    bf8v u0 = *(const bf8v*)&sUE[p * 16 + cl][quad * 8];
                    bf8v u1 = *(const bf8v*)&sUE[p * 16 + cl][32 + quad * 8];
                    f4v acc = {0.f, 0.f, 0.f, 0.f};
                    acc = __builtin_amdgcn_mfma_f32_16x16x32_bf16(a0, u0, acc, 0, 0, 0);
                    acc = __builtin_amdgcn_mfma_f32_16x16x32_bf16(a1, u1, acc, 0, 0, 0);
                    const int kk = hl * 8 + (cl & 7) + (cl >> 3) * 16;
                    #pragma unroll
                    for (int j = 0; j < 4; ++j) {
                        float v = acc[j] * 0.125f;
                        float mx = v;
                        mx = fmaxf(mx, __shfl_xor(mx, 1));
                        mx = fmaxf(mx, __shfl_xor(mx, 2));
                        mx = fmaxf(mx, __shfl_xor(mx, 4));
                        float ex = __expf(v - mx);
                        float sm = ex;
                        sm += __shfl_xor(sm, 1);
                        sm += __shfl_xor(sm, 2);
                        sm += __shfl_xor(sm, 4);
                        float aw = valid ? ex / sm : 0.f;
                        sAblk[p][quad * 4 + j][kk] = f2bf(aw);
                    }
                }
            }
            __syncthreads();

            // ---- PV: accO += Ablk @ Zt (wave = pair) ----
            {
                const int p = wv;
                bf8v a0 = *(const bf8v*)&sAblk[p][cl][quad * 8];
                #pragma unroll
                for (int nt = 0; nt < 4; ++nt) {
                    bf8v bz = *(const bf8v*)&sZt[p][nt * 16 + cl][quad * 8];
                    accO[nt] = __builtin_amdgcn_mfma_f32_16x16x32_bf16(a0, bz, accO[nt], 0, 0, 0);
                }
            }
            __syncthreads();
        }

        // ---- +lin_b, LayerNorm per row over 64 cols, accumulate over l ----
        {
            float x[16];
            #pragma unroll
            for (int nt = 0; nt < 4; ++nt)
                #pragma unroll
                for (int j = 0; j < 4; ++j)
                    x[nt * 4 + j] = accO[nt][j] + sLinb[nt * 16 + cl];
            #pragma unroll
            for (int j = 0; j < 4; ++j) {
                float s = x[j] + x[4 + j] + x[8 + j] + x[12 + j];
                #pragma unroll
                for (int m = 1; m < 16; m <<= 1) s += __shfl_xor(s, m);
                float mean = s * (1.f / 64.f);
                float q = 0.f;
                #pragma unroll
                for (int nt = 0; nt < 4; ++nt) { float d = x[nt * 4 + j] - mean; q += d * d; }
                #pragma unroll
                for (int m = 1; m < 16; m <<= 1) q += __shfl_xor(q, m);
                float rst = rsqrtf(q * (1.f / 64.f) + LN_EPS);
                #pragma unroll
                for (int nt = 0; nt < 4; ++nt) {
                    int col = nt * 16 + cl;
                    lnacc[nt * 4 + j] += (x[nt * 4 + j] - mean) * rst * sLng[col] + sLnb[col];
                }
            }
        }
        __syncthreads();
    }

    // ---- accumulate into ubs_acc ----
    #pragma unroll
    for (int j = 0; j < 4; ++j) {
        const int row = wv * 16 + quad * 4 + j;
        const int b = b0 + (row >> 3), f = row & 7;
        #pragma unroll
        for (int nt = 0; nt < 4; ++nt)
            atomicAdd(&ubs_acc[(size_t)b * 512 + f * 64 + nt * 16 + cl], lnacc[nt * 4 + j]);
    }
}

// ---------------------------------------------------------------------------
// helpers for the fused tower
// ---------------------------------------------------------------------------
__device__ __forceinline__ float block_reduce_sum(float v, float* sRed) {
    #pragma unroll
    for (int m = 1; m < 64; m <<= 1) v += __shfl_xor(v, m, 64);
    int wave = threadIdx.x >> 6, lane = threadIdx.x & 63;
    __syncthreads();
    if (lane == 0) sRed[wave] = v;
    __syncthreads();
    return sRed[0] + sRed[1] + sRed[2] + sRed[3];
}

__device__ __forceinline__ void gemm_stage(
    const unsigned short* __restrict__ A, const unsigned short* __restrict__ Bw,
    const float* __restrict__ bias, float* __restrict__ Cout,
    int K, int N, int m0, int n0)
{
    const int lane = threadIdx.x & 63, quad = lane >> 4, cl = lane & 15;
    f4v acc = {0.f, 0.f, 0.f, 0.f};
    const unsigned short* arow = A + (size_t)(m0 + cl) * K + quad * 8;
    const unsigned short* brow = Bw + (size_t)(n0 + cl) * K + quad * 8;
    for (int k0 = 0; k0 < K; k0 += 32) {
        bf8v a = *(const bf8v*)(arow + k0);
        bf8v b = *(const bf8v*)(brow + k0);
        acc = __builtin_amdgcn_mfma_f32_16x16x32_bf16(a, b, acc, 0, 0, 0);
    }
    float bv = bias[n0 + cl];
    #pragma unroll
    for (int j = 0; j < 4; ++j)
        Cout[(size_t)(m0 + quad * 4 + j) * N + n0 + cl] = acc[j] + bv;
}

__device__ __forceinline__ void ln_stage(
    const float* __restrict__ Cin, const float* __restrict__ g,
    const float* __restrict__ bb, unsigned short* __restrict__ Hx,
    int N, int b, float* sRed)
{
    const int t = threadIdx.x;
    float s = 0.f, s2 = 0.f;
    for (int j = t; j < N; j += 256) { float x = Cin[(size_t)b * N + j]; s += x; s2 += x * x; }
    s  = block_reduce_sum(s,  sRed);
    s2 = block_reduce_sum(s2, sRed);
    float invN = 1.f / (float)N;
    float mean = s * invN;
    float var  = s2 * invN - mean * mean;
    float rst  = rsqrtf(fmaxf(var, 0.f) + LN_EPS);
    for (int j = t; j < N; j += 256) {
        float x = Cin[(size_t)b * N + j];
        Hx[(size_t)b * N + j] = f2bf(fmaxf((x - mean) * rst * g[j] + bb[j], 0.f));
    }
}

// ---------------------------------------------------------------------------
// Kernel T: fully fused tower (cooperative).  grid = 256 blocks x 256 thr.
// stages: reduce+gather X | G1 | LN1 | G2 | LN2 | G3 | final
// ---------------------------------------------------------------------------
__global__ __launch_bounds__(256) void tower_kernel(
    const float* __restrict__ ubs_acc,
    const int* __restrict__ target_ad, const int* __restrict__ profile_feature,
    const float* __restrict__ context,
    const float* __restrict__ item_tables, const float* __restrict__ profile_tables,
    unsigned short* __restrict__ X,
    const unsigned short* __restrict__ Wt1, const float* __restrict__ b1,
    const float* __restrict__ g1, const float* __restrict__ bb1,
    const unsigned short* __restrict__ Wt2, const float* __restrict__ b2,
    const float* __restrict__ g2, const float* __restrict__ bb2,
    const unsigned short* __restrict__ Wt3, const float* __restrict__ b3,
    const float* __restrict__ g3, const float* __restrict__ bb3,
    const float* __restrict__ w4, const float* __restrict__ b4,
    float* __restrict__ C1, unsigned short* __restrict__ H1,
    float* __restrict__ C2, unsigned short* __restrict__ H2,
    float* __restrict__ C3, float* __restrict__ out)
{
    cg::grid_group grid = cg::this_grid();
    __shared__ float sRed[4];
    const int bx = blockIdx.x, t = threadIdx.x;
    const int wv = t >> 6;

    // ---- stage R: ubs = relu(acc/L), gather concat -> X bf16 ----
    {
        const int b = bx;
        const float2 v = *(const float2*)(ubs_acc + (size_t)b * 512 + t * 2);
        X[b * TOWER_IN_ + t * 2]     = f2bf(fmaxf(v.x * 0.01f, 0.f));
        X[b * TOWER_IN_ + t * 2 + 1] = f2bf(fmaxf(v.y * 0.01f, 0.f));
        for (int cc = 512 + t; cc < TOWER_IN_; cc += 256) {
            float x;
            if (cc < 1024) { int j = cc - 512, f = j >> 6, e = j & 63;
                x = item_tables[((size_t)f * V_ + target_ad[b * 8 + f]) * 64 + e]; }
            else if (cc < 1280) { int j = cc - 1024, pp = j >> 6, e = j & 63;
                x = profile_tables[((size_t)pp * V_ + profile_feature[b * 4 + pp]) * 64 + e]; }
            else x = context[b * 32 + (cc - 1280)];
            X[b * TOWER_IN_ + cc] = f2bf(x);
        }
    }
    grid.sync();

    // ---- stage G1: C1 = X @ Wt1 + b1   (M=256,N=1024,K=1312) ----
    gemm_stage(X, Wt1, b1, C1, 1312, 1024, (bx >> 4) * 16, (bx & 15) * 64 + wv * 16);
    grid.sync();

    // ---- stage LN1 -> H1 ----
    ln_stage(C1, g1, bb1, H1, 1024, bx, sRed);
    grid.sync();

    // ---- stage G2: C2 = H1 @ Wt2 + b2  (M=256,N=512,K=1024) ----
    if (wv < 2)
        gemm_stage(H1, Wt2, b2, C2, 1024, 512, (bx >> 4) * 16, (bx & 15) * 32 + wv * 16);
    grid.sync();

    // ---- stage LN2 -> H2 ----
    ln_stage(C2, g2, bb2, H2, 512, bx, sRed);
    grid.sync();

    // ---- stage G3: C3 = H2 @ Wt3 + b3  (M=256,N=256,K=512) ----
    if (wv == 0)
        gemm_stage(H2, Wt3, b3, C3, 512, 256, (bx >> 4) * 16, (bx & 15) * 16);
    grid.sync();

    // ---- stage F: final LN + ReLU + dot(w4) + sigmoid ----
    {
        const int b = bx;
        float x = C3[b * 256 + t];
        float s = block_reduce_sum(x, sRed);
        float mean = s * (1.f / 256.f);
        float d = x - mean;
        float q = block_reduce_sum(d * d, sRed);
        float rst = rsqrtf(q * (1.f / 256.f) + LN_EPS);
        float h = fmaxf(d * rst * g3[t] + bb3[t], 0.f);
        float p = block_reduce_sum(h * w4[t], sRed);
        if (t == 0) out[b] = 1.f / (1.f + expf(-(p + b4[0])));
    }
}

// ---------------------------------------------------------------------------
extern "C" void kernel_launch(void* const* d_in, const int* in_sizes, int n_in,
                              void* d_out, int out_size, void* d_ws, size_t ws_size,
                              hipStream_t stream)
{
    (void)in_sizes; (void)n_in; (void)out_size; (void)ws_size;
    const int*   target_ad       = (const int*)d_in[0];
    const int*   ubs_feature     = (const int*)d_in[1];
    const int*   profile_feature = (const int*)d_in[2];
    const float* context         = (const float*)d_in[3];
    const float* item_tables     = (const float*)d_in[4];
    const float* profile_tables  = (const float*)d_in[5];
    const float* q_w   = (const float*)d_in[6];
    const float* k_w   = (const float*)d_in[7];
    const float* v_w   = (const float*)d_in[8];
    const float* lin_w = (const float*)d_in[9];
    const float* lin_b = (const float*)d_in[10];
    const float* ln_g  = (const float*)d_in[11];
    const float* ln_b  = (const float*)d_in[12];
    const float* t_w1  = (const float*)d_in[13];
    const float* t_b1  = (const float*)d_in[14];
    const float* t_g1  = (const float*)d_in[15];
    const float* t_bb1 = (const float*)d_in[16];
    const float* t_w2  = (const float*)d_in[17];
    const float* t_b2  = (const float*)d_in[18];
    const float* t_g2  = (const float*)d_in[19];
    const float* t_bb2 = (const float*)d_in[20];
    const float* t_w3  = (const float*)d_in[21];
    const float* t_b3  = (const float*)d_in[22];
    const float* t_g3  = (const float*)d_in[23];
    const float* t_bb3 = (const float*)d_in[24];
    const float* t_w4  = (const float*)d_in[25];
    const float* t_b4  = (const float*)d_in[26];

    char* ws = (char*)d_ws;
    unsigned short* wsMT = (unsigned short*)(ws);              //  3,276,800
    unsigned short* wsWT = (unsigned short*)(ws +  3276800);   //  3,276,800
    float* ubs_acc       = (float*)         (ws +  6553600);   //    524,288
    unsigned short* Wt1  = (unsigned short*)(ws +  7077888);   //  2,686,976
    unsigned short* Wt2  = (unsigned short*)(ws +  9764864);   //  1,048,576
    unsigned short* Wt3  = (unsigned short*)(ws + 10813440);   //    262,144
    unsigned short* X    = (unsigned short*)(ws + 11075584);   //    671,744
    float*          C1   = (float*)         (ws + 11747328);   //  1,048,576
    unsigned short* H1   = (unsigned short*)(ws + 12795904);   //    524,288
    float*          C2   = (float*)         (ws + 13320192);   //    524,288
    unsigned short* H2   = (unsigned short*)(ws + 13844480);   //    262,144
    float*          C3   = (float*)         (ws + 14106624);   //    262,144 (end 14,368,768)

    setup_kernel<<<2368, 256, 0, stream>>>(q_w, k_w, v_w, lin_w, t_w1, t_w2, t_w3,
                                           wsMT, wsWT, Wt1, Wt2, Wt3, ubs_acc);
    attn_kernel<<<NCH_ * 32, 256, 0, stream>>>(ubs_feature, item_tables, wsMT, wsWT,
                                               lin_b, ln_g, ln_b, ubs_acc);
    {
        const float* ubs_acc_c = ubs_acc;
        void* args[] = {
            (void*)&ubs_acc_c, (void*)&target_ad, (void*)&profile_feature, (void*)&context,
            (void*)&item_tables, (void*)&profile_tables, (void*)&X,
            (void*)&Wt1, (void*)&t_b1, (void*)&t_g1, (void*)&t_bb1,
            (void*)&Wt2, (void*)&t_b2, (void*)&t_g2, (void*)&t_bb2,
            (void*)&Wt3, (void*)&t_b3, (void*)&t_g3, (void*)&t_bb3,
            (void*)&t_w4, (void*)&t_b4,
            (void*)&C1, (void*)&H1, (void*)&C2, (void*)&H2, (void*)&C3,
            (void*)&d_out
        };
        hipLaunchCooperativeKernel((const void*)tower_kernel, dim3(256), dim3(256),
                                   args, 0, stream);
    }
}

// Round 7
// 319.111 us; speedup vs baseline: 1.3922x; 1.3922x over previous
//
#include <hip/hip_runtime.h>
#include <hip/hip_bf16.h>

#define B_ 256
#define L_ 100
#define F_ 8
#define P_ 4
#define E_ 64
#define H_ 4
#define D_ 64
#define C_ 32
#define V_ 10000
#define TOWER_IN_ 1312
#define LN_EPS 0.001f
#define LCH_ 4    // l's per attention block
#define NCH_ 25   // number of l-chunks

typedef __attribute__((ext_vector_type(8))) short bf8v;   // 8 bf16 (4 VGPRs)
typedef __attribute__((ext_vector_type(4))) float f4v;    // 4 f32 acc

__device__ __forceinline__ unsigned short f2bf(float x) {
    __hip_bfloat16 h = __float2bfloat16(x);
    return __builtin_bit_cast(unsigned short, h);
}

// ---------------------------------------------------------------------------
// Kernel S: fused setup.  grid = 2369 blocks, 256 thr.
//   bx < 1952          : transpose tower weights to bf16 [n][k]
//   1952 <= bx < 2352  : precompute MT/WT (MFMA)
//   2352 <= bx < 2368  : zero ubs_acc
//   bx == 2368         : zero stats1/stats2
// ---------------------------------------------------------------------------
__global__ __launch_bounds__(256) void setup_kernel(
    const float* __restrict__ q_w, const float* __restrict__ k_w,
    const float* __restrict__ v_w, const float* __restrict__ lin_w,
    const float* __restrict__ w1, const float* __restrict__ w2,
    const float* __restrict__ w3,
    unsigned short* __restrict__ wsMT, unsigned short* __restrict__ wsWT,
    unsigned short* __restrict__ Wt1, unsigned short* __restrict__ Wt2,
    unsigned short* __restrict__ Wt3, float* __restrict__ ubs_acc,
    float* __restrict__ stats)
{
    __shared__ float tile[32][33];
    __shared__ __align__(16) unsigned short sX[64][72];
    __shared__ __align__(16) unsigned short sY[64][72];
    const int bx = blockIdx.x, t = threadIdx.x;

    if (bx < 1952) {
        const float* src; unsigned short* dst; int K, N, tk, tn;
        if (bx < 1312)      { src = w1; dst = Wt1; K = 1312; N = 1024; tk = bx / 32;  tn = bx % 32; }
        else if (bx < 1824) { int i = bx - 1312; src = w2; dst = Wt2; K = 1024; N = 512; tk = i / 16; tn = i % 16; }
        else                { int i = bx - 1824; src = w3; dst = Wt3; K = 512;  N = 256; tk = i / 8;  tn = i % 8; }
        const int k0 = tk * 32, n0 = tn * 32;
        const int rr = t >> 5, cc = t & 31;
        #pragma unroll
        for (int i = 0; i < 4; ++i) {
            int r = rr * 4 + i;
            tile[r][cc] = src[(size_t)(k0 + r) * N + n0 + cc];
        }
        __syncthreads();
        #pragma unroll
        for (int i = 0; i < 4; ++i) {
            int r = rr * 4 + i;
            dst[(size_t)(n0 + r) * K + k0 + cc] = f2bf(tile[cc][r]);
        }
    } else if (bx < 2352) {
        const int lh = bx - 1952;
        const int l = lh >> 2, h = lh & 3;
        const size_t obase = (size_t)lh * 4096;
        const int wv = t >> 6, lane = t & 63, quad = lane >> 4, cl = lane & 15;
        const int r = t >> 2, seg = t & 3, e0s = seg * 16;

        // phase 1: sX = K rows, sY = Q rows ; MT[o][e] = sum_d Q[e][d]K[o][d]
        #pragma unroll
        for (int j = 0; j < 8; ++j) {
            const float* kp = k_w + (size_t)(l * 64 + r) * 256 + h * 64 + e0s + 2 * j;
            const float* qp = q_w + (size_t)(l * 64 + r) * 256 + h * 64 + e0s + 2 * j;
            *(unsigned*)&sX[r][e0s + 2 * j] = (unsigned)f2bf(kp[0]) | ((unsigned)f2bf(kp[1]) << 16);
            *(unsigned*)&sY[r][e0s + 2 * j] = (unsigned)f2bf(qp[0]) | ((unsigned)f2bf(qp[1]) << 16);
        }
        __syncthreads();
        {
            const int o0 = wv * 16;
            #pragma unroll
            for (int nt = 0; nt < 4; ++nt) {
                f4v acc = {0.f, 0.f, 0.f, 0.f};
                #pragma unroll
                for (int k2 = 0; k2 < 2; ++k2) {
                    bf8v a = *(const bf8v*)&sX[o0 + cl][k2 * 32 + quad * 8];
                    bf8v b = *(const bf8v*)&sY[nt * 16 + cl][k2 * 32 + quad * 8];
                    acc = __builtin_amdgcn_mfma_f32_16x16x32_bf16(a, b, acc, 0, 0, 0);
                }
                #pragma unroll
                for (int j = 0; j < 4; ++j)
                    wsMT[obase + (size_t)(o0 + quad * 4 + j) * 64 + nt * 16 + cl] = f2bf(acc[j]);
            }
        }
        __syncthreads();
        // phase 2: sX = L^T rows [o][d], sY = V rows [e][d]; WT[o][e]=sum_d L[d][o]V[e][d]
        {
            const int o = t & 63, db = t >> 6;
            #pragma unroll
            for (int j = 0; j < 16; ++j) {
                int d = db * 16 + j;
                sX[o][d] = f2bf(lin_w[(size_t)l * 16384 + (h * 64 + d) * 64 + o]);
            }
        }
        #pragma unroll
        for (int j = 0; j < 8; ++j) {
            const float* vp = v_w + (size_t)(l * 64 + r) * 256 + h * 64 + e0s + 2 * j;
            *(unsigned*)&sY[r][e0s + 2 * j] = (unsigned)f2bf(vp[0]) | ((unsigned)f2bf(vp[1]) << 16);
        }
        __syncthreads();
        {
            const int o0 = wv * 16;
            #pragma unroll
            for (int nt = 0; nt < 4; ++nt) {
                f4v acc = {0.f, 0.f, 0.f, 0.f};
                #pragma unroll
                for (int k2 = 0; k2 < 2; ++k2) {
                    bf8v a = *(const bf8v*)&sX[o0 + cl][k2 * 32 + quad * 8];
                    bf8v b = *(const bf8v*)&sY[nt * 16 + cl][k2 * 32 + quad * 8];
                    acc = __builtin_amdgcn_mfma_f32_16x16x32_bf16(a, b, acc, 0, 0, 0);
                }
                #pragma unroll
                for (int j = 0; j < 4; ++j)
                    wsWT[obase + (size_t)(o0 + quad * 4 + j) * 64 + nt * 16 + cl] = f2bf(acc[j]);
            }
        }
    } else if (bx < 2368) {
        const int idx = (bx - 2352) * 256 + t;
        for (int i = idx; i < B_ * F_ * E_; i += 16 * 256) ubs_acc[i] = 0.f;
    } else {
        #pragma unroll
        for (int i = 0; i < 4; ++i) stats[t + i * 256] = 0.f;   // 1024 floats
    }
}

// ---------------------------------------------------------------------------
// Kernel A: fused attention (R5 structure + pad40 + fewer barriers + prefetch)
// grid = NCH_*32 blocks (block = 8 b's x LCH_ l's), 256 threads = 4 waves.
// ---------------------------------------------------------------------------
__global__ __launch_bounds__(256, 3) void attn_kernel(
    const int* __restrict__ ubs_feature, const float* __restrict__ item_tables,
    const unsigned short* __restrict__ wsMT, const unsigned short* __restrict__ wsWT,
    const float* __restrict__ lin_b, const float* __restrict__ ln_g,
    const float* __restrict__ ln_b, float* __restrict__ ubs_acc)
{
    __shared__ __align__(16) unsigned short sUE[64][72];       // rows=b_loc*8+f
    __shared__ __align__(16) unsigned short sT[64][136];       // cols=hl*64+e'
    __shared__ __align__(16) unsigned short sZt[4][64][40];    // [pair][e][k] pad40
    __shared__ __align__(16) unsigned short sAblk[4][16][40];  // [pair][r][k] pad40
    __shared__ float sLng[64], sLnb[64], sLinb[64];

    const int t = threadIdx.x;
    const int c = blockIdx.x >> 5;            // l-chunk 0..NCH_-1
    const int b0 = (blockIdx.x & 31) * 8;
    const int wv = t >> 6, lane = t & 63, quad = lane >> 4, cl = lane & 15;
    const int grow = t >> 2, gseg = t & 3, ge0 = gseg * 16;
    const int gbl = grow >> 3, gfq = grow & 7;
    const int gbg = b0 + gbl;
    const int role = wv >> 1;                 // 0=T, 1=Z
    const int hlw  = wv & 1;

    if (t < 64) { sLng[t] = ln_g[t]; sLnb[t] = ln_b[t]; }

    float lnacc[16];
    #pragma unroll
    for (int i = 0; i < 16; ++i) lnacc[i] = 0.f;

    // prefetch gather for first l
    float2 pf[8];
    {
        const int l = c * LCH_;
        const int vidx = ubs_feature[(gbg * L_ + l) * F_ + gfq];
        const float* srcp = item_tables + ((size_t)gfq * V_ + vidx) * 64 + ge0;
        #pragma unroll
        for (int j = 0; j < 8; ++j) pf[j] = *(const float2*)(srcp + 2 * j);
    }

    for (int li = 0; li < LCH_; ++li) {
        const int l = c * LCH_ + li;
        if (t >= 64 && t < 128) sLinb[t - 64] = lin_b[l * 64 + (t - 64)];

        // ---- commit prefetched UE rows (f32 -> bf16) ----
        #pragma unroll
        for (int j = 0; j < 8; ++j) {
            unsigned u = (unsigned)f2bf(pf[j].x) | ((unsigned)f2bf(pf[j].y) << 16);
            *(unsigned*)&sUE[grow][ge0 + 2 * j] = u;
        }

        // ---- hoist both halves' B-fragments for this l (overlaps barrier) ----
        bf8v bfrag[2][4][2];
        #pragma unroll
        for (int half = 0; half < 2; ++half) {
            const unsigned short* Bsrc =
                (role == 0 ? wsMT : wsWT) + (size_t)(l * 4 + half * 2 + hlw) * 4096;
            #pragma unroll
            for (int nt = 0; nt < 4; ++nt)
                #pragma unroll
                for (int k2 = 0; k2 < 2; ++k2)
                    bfrag[half][nt][k2] =
                        *(const bf8v*)(Bsrc + (nt * 16 + cl) * 64 + k2 * 32 + quad * 8);
        }
        __syncthreads();   // gather visible

        // ---- prefetch next l's gather ----
        if (li + 1 < LCH_) {
            const int ln = l + 1;
            const int vidx = ubs_feature[(gbg * L_ + ln) * F_ + gfq];
            const float* srcp = item_tables + ((size_t)gfq * V_ + vidx) * 64 + ge0;
            #pragma unroll
            for (int j = 0; j < 8; ++j) pf[j] = *(const float2*)(srcp + 2 * j);
        }

        f4v accO[4];
        #pragma unroll
        for (int nt = 0; nt < 4; ++nt) accO[nt] = {0.f, 0.f, 0.f, 0.f};

        #pragma unroll
        for (int half = 0; half < 2; ++half) {
            // ---- phase A: waves 0,1 -> T (h=hlw); waves 2,3 -> Zt ----
            #pragma unroll
            for (int m = 0; m < 4; ++m) {
                bf8v a0 = *(const bf8v*)&sUE[m * 16 + cl][quad * 8];
                bf8v a1 = *(const bf8v*)&sUE[m * 16 + cl][32 + quad * 8];
                #pragma unroll
                for (int nt = 0; nt < 4; ++nt) {
                    f4v acc = {0.f, 0.f, 0.f, 0.f};
                    acc = __builtin_amdgcn_mfma_f32_16x16x32_bf16(a0, bfrag[half][nt][0], acc, 0, 0, 0);
                    acc = __builtin_amdgcn_mfma_f32_16x16x32_bf16(a1, bfrag[half][nt][1], acc, 0, 0, 0);
                    if (role == 0) {
                        #pragma unroll
                        for (int j = 0; j < 4; ++j)
                            sT[m * 16 + quad * 4 + j][hlw * 64 + nt * 16 + cl] = f2bf(acc[j]);
                    } else {
                        ushort4 zp;
                        zp.x = f2bf(acc[0]); zp.y = f2bf(acc[1]);
                        zp.z = f2bf(acc[2]); zp.w = f2bf(acc[3]);
                        const int k0 = (quad >> 1) * 16 + hlw * 8 + (quad & 1) * 4;
                        *(ushort4*)&sZt[m][nt * 16 + cl][k0] = zp;
                    }
                }
            }
            __syncthreads();

            // ---- scores + softmax + Ablk (wave = pair) ----
            {
                const int p = wv;
                const bool valid = (cl >> 3) == (quad >> 1);
                #pragma unroll
                for (int hl = 0; hl < 2; ++hl) {
                    bf8v a0 = *(const bf8v*)&sT[p * 16 + cl][hl * 64 + quad * 8];
                    bf8v a1 = *(const bf8v*)&sT[p * 16 + cl][hl * 64 + 32 + quad * 8];
                    bf8v u0 = *(const bf8v*)&sUE[p * 16 + cl][quad * 8];
                    bf8v u1 = *(const bf8v*)&sUE[p * 16 + cl][32 + quad * 8];
                    f4v acc = {0.f, 0.f, 0.f, 0.f};
                    acc = __builtin_amdgcn_mfma_f32_16x16x32_bf16(a0, u0, acc, 0, 0, 0);
                    acc = __builtin_amdgcn_mfma_f32_16x16x32_bf16(a1, u1, acc, 0, 0, 0);
                    const int kk = hl * 8 + (cl & 7) + (cl >> 3) * 16;
                    #pragma unroll
                    for (int j = 0; j < 4; ++j) {
                        float v = acc[j] * 0.125f;
                        float mx = v;
                        mx = fmaxf(mx, __shfl_xor(mx, 1));
                        mx = fmaxf(mx, __shfl_xor(mx, 2));
                        mx = fmaxf(mx, __shfl_xor(mx, 4));
                        float ex = __expf(v - mx);
                        float sm = ex;
                        sm += __shfl_xor(sm, 1);
                        sm += __shfl_xor(sm, 2);
                        sm += __shfl_xor(sm, 4);
                        float aw = valid ? ex / sm : 0.f;
                        sAblk[p][quad * 4 + j][kk] = f2bf(aw);
                    }
                }
            }
            // NO barrier: sAblk[p] is same-wave produce/consume

            // ---- PV: accO += Ablk @ Zt (wave = pair) ----
            {
                const int p = wv;
                bf8v a0 = *(const bf8v*)&sAblk[p][cl][quad * 8];
                #pragma unroll
                for (int nt = 0; nt < 4; ++nt) {
                    bf8v bz = *(const bf8v*)&sZt[p][nt * 16 + cl][quad * 8];
                    accO[nt] = __builtin_amdgcn_mfma_f32_16x16x32_bf16(a0, bz, accO[nt], 0, 0, 0);
                }
            }
            if (half == 0) __syncthreads();   // protect sT/sZt for half1 rewrite
        }

        // ---- +lin_b, LayerNorm per row over 64 cols, accumulate over l ----
        {
            float x[16];
            #pragma unroll
            for (int nt = 0; nt < 4; ++nt)
                #pragma unroll
                for (int j = 0; j < 4; ++j)
                    x[nt * 4 + j] = accO[nt][j] + sLinb[nt * 16 + cl];
            #pragma unroll
            for (int j = 0; j < 4; ++j) {
                float s = x[j] + x[4 + j] + x[8 + j] + x[12 + j];
                #pragma unroll
                for (int m = 1; m < 16; m <<= 1) s += __shfl_xor(s, m);
                float mean = s * (1.f / 64.f);
                float q = 0.f;
                #pragma unroll
                for (int nt = 0; nt < 4; ++nt) { float d = x[nt * 4 + j] - mean; q += d * d; }
                #pragma unroll
                for (int m = 1; m < 16; m <<= 1) q += __shfl_xor(q, m);
                float rst = rsqrtf(q * (1.f / 64.f) + LN_EPS);
                #pragma unroll
                for (int nt = 0; nt < 4; ++nt) {
                    int col = nt * 16 + cl;
                    lnacc[nt * 4 + j] += (x[nt * 4 + j] - mean) * rst * sLng[col] + sLnb[col];
                }
            }
        }
        __syncthreads();   // protect sUE/sZt/sT before next l
    }

    #pragma unroll
    for (int j = 0; j < 4; ++j) {
        const int row = wv * 16 + quad * 4 + j;
        const int b = b0 + (row >> 3), f = row & 7;
        #pragma unroll
        for (int nt = 0; nt < 4; ++nt)
            atomicAdd(&ubs_acc[(size_t)b * 512 + f * 64 + nt * 16 + cl], lnacc[nt * 4 + j]);
    }
}

// ---------------------------------------------------------------------------
// Kernel G1: gather/concat + GEMM(1312->1024) + bias + row stats (atomics).
// grid = dim3(16 n-tiles, 16 m-tiles), 256 thr.
// ---------------------------------------------------------------------------
__global__ __launch_bounds__(256) void gemm1_kernel(
    const float* __restrict__ ubs_acc,
    const int* __restrict__ target_ad, const int* __restrict__ profile_feature,
    const float* __restrict__ context,
    const float* __restrict__ item_tables, const float* __restrict__ profile_tables,
    const unsigned short* __restrict__ Wt1, const float* __restrict__ b1,
    float* __restrict__ C1, float* __restrict__ stats1)
{
    __shared__ __align__(16) unsigned short sA[16][1320];
    const int t = threadIdx.x;
    const int m0 = blockIdx.y * 16;
    const int r = t >> 4, c0 = t & 15;
    const int b = m0 + r;

    for (int cc = c0; cc < TOWER_IN_; cc += 16) {
        float x;
        if (cc < 512) x = fmaxf(ubs_acc[(size_t)b * 512 + cc] * 0.01f, 0.f);
        else if (cc < 1024) { int j = cc - 512, f = j >> 6, e = j & 63;
            x = item_tables[((size_t)f * V_ + target_ad[b * 8 + f]) * 64 + e]; }
        else if (cc < 1280) { int j = cc - 1024, pp = j >> 6, e = j & 63;
            x = profile_tables[((size_t)pp * V_ + profile_feature[b * 4 + pp]) * 64 + e]; }
        else x = context[b * 32 + (cc - 1280)];
        sA[r][cc] = f2bf(x);
    }
    __syncthreads();

    const int wv = t >> 6, lane = t & 63, quad = lane >> 4, cl = lane & 15;
    const int n0 = blockIdx.x * 64 + wv * 16;
    f4v acc = {0.f, 0.f, 0.f, 0.f};
    const unsigned short* brow = Wt1 + (size_t)(n0 + cl) * 1312 + quad * 8;
    for (int k0 = 0; k0 < 1312; k0 += 32) {
        bf8v a  = *(const bf8v*)&sA[cl][k0 + quad * 8];
        bf8v bf = *(const bf8v*)(brow + k0);
        acc = __builtin_amdgcn_mfma_f32_16x16x32_bf16(a, bf, acc, 0, 0, 0);
    }
    const float bv = b1[n0 + cl];
    #pragma unroll
    for (int j = 0; j < 4; ++j) {
        float v = acc[j] + bv;
        C1[(size_t)(m0 + quad * 4 + j) * 1024 + n0 + cl] = v;
        float s = v, s2 = v * v;
        #pragma unroll
        for (int m = 1; m < 16; m <<= 1) { s += __shfl_xor(s, m, 16); s2 += __shfl_xor(s2, m, 16); }
        if (cl == 0) {
            atomicAdd(&stats1[(m0 + quad * 4 + j) * 2],     s);
            atomicAdd(&stats1[(m0 + quad * 4 + j) * 2 + 1], s2);
        }
    }
}

// ---------------------------------------------------------------------------
// Kernel G2: inline LN1+ReLU build + GEMM(1024->512) + bias + row stats.
// grid = dim3(8, 16), 256 thr.
// ---------------------------------------------------------------------------
__global__ __launch_bounds__(256) void gemm2_kernel(
    const float* __restrict__ C1, const float* __restrict__ stats1,
    const float* __restrict__ g1, const float* __restrict__ bb1,
    const unsigned short* __restrict__ Wt2, const float* __restrict__ b2,
    float* __restrict__ C2, float* __restrict__ stats2)
{
    __shared__ __align__(16) unsigned short sA[16][1032];
    const int t = threadIdx.x;
    const int m0 = blockIdx.y * 16;
    const int r = t >> 4, c0 = t & 15;
    const int row = m0 + r;
    {
        const float s = stats1[row * 2], s2 = stats1[row * 2 + 1];
        const float mean = s * (1.f / 1024.f);
        const float var  = s2 * (1.f / 1024.f) - mean * mean;
        const float rst  = rsqrtf(fmaxf(var, 0.f) + LN_EPS);
        for (int cc = c0; cc < 1024; cc += 16) {
            float x = C1[(size_t)row * 1024 + cc];
            sA[r][cc] = f2bf(fmaxf((x - mean) * rst * g1[cc] + bb1[cc], 0.f));
        }
    }
    __syncthreads();

    const int wv = t >> 6, lane = t & 63, quad = lane >> 4, cl = lane & 15;
    const int n0 = blockIdx.x * 64 + wv * 16;
    f4v acc = {0.f, 0.f, 0.f, 0.f};
    const unsigned short* brow = Wt2 + (size_t)(n0 + cl) * 1024 + quad * 8;
    for (int k0 = 0; k0 < 1024; k0 += 32) {
        bf8v a  = *(const bf8v*)&sA[cl][k0 + quad * 8];
        bf8v bf = *(const bf8v*)(brow + k0);
        acc = __builtin_amdgcn_mfma_f32_16x16x32_bf16(a, bf, acc, 0, 0, 0);
    }
    const float bv = b2[n0 + cl];
    #pragma unroll
    for (int j = 0; j < 4; ++j) {
        float v = acc[j] + bv;
        C2[(size_t)(m0 + quad * 4 + j) * 512 + n0 + cl] = v;
        float s = v, s2 = v * v;
        #pragma unroll
        for (int m = 1; m < 16; m <<= 1) { s += __shfl_xor(s, m, 16); s2 += __shfl_xor(s2, m, 16); }
        if (cl == 0) {
            atomicAdd(&stats2[(m0 + quad * 4 + j) * 2],     s);
            atomicAdd(&stats2[(m0 + quad * 4 + j) * 2 + 1], s2);
        }
    }
}

// ---------------------------------------------------------------------------
// Kernel G3F: inline LN2+ReLU build + GEMM(512->256) + final LN + dot + sigmoid.
// grid = 16 blocks (m-tiles), 256 thr.  Each block owns 16 b's end-to-end.
// ---------------------------------------------------------------------------
__global__ __launch_bounds__(256) void gemm3f_kernel(
    const float* __restrict__ C2, const float* __restrict__ stats2,
    const float* __restrict__ g2, const float* __restrict__ bb2,
    const unsigned short* __restrict__ Wt3, const float* __restrict__ b3,
    const float* __restrict__ g3, const float* __restrict__ bb3,
    const float* __restrict__ w4, const float* __restrict__ b4,
    float* __restrict__ out)
{
    __shared__ __align__(16) unsigned short sA[16][520];
    __shared__ float sC[16][260];
    const int t = threadIdx.x;
    const int m0 = blockIdx.x * 16;
    const int r = t >> 4, c0 = t & 15;
    const int row = m0 + r;
    {
        const float s = stats2[row * 2], s2 = stats2[row * 2 + 1];
        const float mean = s * (1.f / 512.f);
        const float var  = s2 * (1.f / 512.f) - mean * mean;
        const float rst  = rsqrtf(fmaxf(var, 0.f) + LN_EPS);
        for (int cc = c0; cc < 512; cc += 16) {
            float x = C2[(size_t)row * 512 + cc];
            sA[r][cc] = f2bf(fmaxf((x - mean) * rst * g2[cc] + bb2[cc], 0.f));
        }
    }
    __syncthreads();

    const int wv = t >> 6, lane = t & 63, quad = lane >> 4, cl = lane & 15;
    #pragma unroll
    for (int nt = 0; nt < 4; ++nt) {
        const int n0 = wv * 64 + nt * 16;
        f4v acc = {0.f, 0.f, 0.f, 0.f};
        const unsigned short* brow = Wt3 + (size_t)(n0 + cl) * 512 + quad * 8;
        for (int k0 = 0; k0 < 512; k0 += 32) {
            bf8v a  = *(const bf8v*)&sA[cl][k0 + quad * 8];
            bf8v bf = *(const bf8v*)(brow + k0);
            acc = __builtin_amdgcn_mfma_f32_16x16x32_bf16(a, bf, acc, 0, 0, 0);
        }
        const float bv = b3[n0 + cl];
        #pragma unroll
        for (int j = 0; j < 4; ++j)
            sC[quad * 4 + j][n0 + cl] = acc[j] + bv;
    }
    __syncthreads();

    // final LN over 256 cols + dot(w4) + sigmoid, 16 threads per row
    float ps = 0.f, ps2 = 0.f;
    for (int cc = c0; cc < 256; cc += 16) { float x = sC[r][cc]; ps += x; ps2 += x * x; }
    #pragma unroll
    for (int m = 1; m < 16; m <<= 1) { ps += __shfl_xor(ps, m, 16); ps2 += __shfl_xor(ps2, m, 16); }
    const float mean = ps * (1.f / 256.f);
    const float var  = ps2 * (1.f / 256.f) - mean * mean;
    const float rst  = rsqrtf(fmaxf(var, 0.f) + LN_EPS);
    float pd = 0.f;
    for (int cc = c0; cc < 256; cc += 16) {
        float x = sC[r][cc];
        float h = fmaxf((x - mean) * rst * g3[cc] + bb3[cc], 0.f);
        pd += h * w4[cc];
    }
    #pragma unroll
    for (int m = 1; m < 16; m <<= 1) pd += __shfl_xor(pd, m, 16);
    if (c0 == 0) out[row] = 1.f / (1.f + expf(-(pd + b4[0])));
}

// ---------------------------------------------------------------------------
extern "C" void kernel_launch(void* const* d_in, const int* in_sizes, int n_in,
                              void* d_out, int out_size, void* d_ws, size_t ws_size,
                              hipStream_t stream)
{
    (void)in_sizes; (void)n_in; (void)out_size; (void)ws_size;
    const int*   target_ad       = (const int*)d_in[0];
    const int*   ubs_feature     = (const int*)d_in[1];
    const int*   profile_feature = (const int*)d_in[2];
    const float* context         = (const float*)d_in[3];
    const float* item_tables     = (const float*)d_in[4];
    const float* profile_tables  = (const float*)d_in[5];
    const float* q_w   = (const float*)d_in[6];
    const float* k_w   = (const float*)d_in[7];
    const float* v_w   = (const float*)d_in[8];
    const float* lin_w = (const float*)d_in[9];
    const float* lin_b = (const float*)d_in[10];
    const float* ln_g  = (const float*)d_in[11];
    const float* ln_b  = (const float*)d_in[12];
    const float* t_w1  = (const float*)d_in[13];
    const float* t_b1  = (const float*)d_in[14];
    const float* t_g1  = (const float*)d_in[15];
    const float* t_bb1 = (const float*)d_in[16];
    const float* t_w2  = (const float*)d_in[17];
    const float* t_b2  = (const float*)d_in[18];
    const float* t_g2  = (const float*)d_in[19];
    const float* t_bb2 = (const float*)d_in[20];
    const float* t_w3  = (const float*)d_in[21];
    const float* t_b3  = (const float*)d_in[22];
    const float* t_g3  = (const float*)d_in[23];
    const float* t_bb3 = (const float*)d_in[24];
    const float* t_w4  = (const float*)d_in[25];
    const float* t_b4  = (const float*)d_in[26];

    char* ws = (char*)d_ws;
    unsigned short* wsMT = (unsigned short*)(ws);              //  3,276,800
    unsigned short* wsWT = (unsigned short*)(ws +  3276800);   //  3,276,800
    float* ubs_acc       = (float*)         (ws +  6553600);   //    524,288
    unsigned short* Wt1  = (unsigned short*)(ws +  7077888);   //  2,686,976
    unsigned short* Wt2  = (unsigned short*)(ws +  9764864);   //  1,048,576
    unsigned short* Wt3  = (unsigned short*)(ws + 10813440);   //    262,144
    float*          C1   = (float*)         (ws + 11075584);   //  1,048,576
    float*          C2   = (float*)         (ws + 12124160);   //    524,288
    float*          stats1 = (float*)       (ws + 12648448);   //      2,048
    float*          stats2 = (float*)       (ws + 12650496);   //      2,048 (end 12,652,544)

    setup_kernel<<<2369, 256, 0, stream>>>(q_w, k_w, v_w, lin_w, t_w1, t_w2, t_w3,
                                           wsMT, wsWT, Wt1, Wt2, Wt3, ubs_acc, stats1);
    attn_kernel<<<NCH_ * 32, 256, 0, stream>>>(ubs_feature, item_tables, wsMT, wsWT,
                                               lin_b, ln_g, ln_b, ubs_acc);
    gemm1_kernel<<<dim3(16, 16), 256, 0, stream>>>(ubs_acc, target_ad, profile_feature,
        context, item_tables, profile_tables, Wt1, t_b1, C1, stats1);
    gemm2_kernel<<<dim3(8, 16), 256, 0, stream>>>(C1, stats1, t_g1, t_bb1,
        Wt2, t_b2, C2, stats2);
    gemm3f_kernel<<<16, 256, 0, stream>>>(C2, stats2, t_g2, t_bb2,
        Wt3, t_b3, t_g3, t_bb3, t_w4, t_b4, (float*)d_out);
}